// Round 1
// baseline (772.280 us; speedup 1.0000x reference)
//
#include <hip/hip_runtime.h>

// GraphSAGEConv: out_i = mean_{j in N(i)} x_j @ W_l + b_l + x_i @ W_r
// N=100000, E=1600000, D_in=D_out=64.
//
// Strategy: counting-sort edges by dst (int atomics only), then one wave per
// node aggregates its neighbor segment without atomics (lane = feature,
// coalesced 256B row gathers), then the 64x64 GEMMs are fused in-wave via
// __shfl broadcast with W_l/W_r staged in LDS.

#define DFEAT 64

__global__ void hist_kernel(const int* __restrict__ dst, int* __restrict__ cnt, int E) {
    int i = blockIdx.x * blockDim.x + threadIdx.x;
    if (i < E) atomicAdd(&cnt[dst[i]], 1);
}

// Single-block exclusive scan over n counters -> off[0..n]
__global__ void scan_kernel(const int* __restrict__ cnt, int* __restrict__ off, int n) {
    const int T = 1024;
    __shared__ int sums[T];
    int t = threadIdx.x;
    int chunk = (n + T - 1) / T;
    int begin = t * chunk;
    int end = begin + chunk; if (end > n) end = n;
    int s = 0;
    for (int i = begin; i < end; ++i) s += cnt[i];
    sums[t] = s;
    __syncthreads();
    // Hillis-Steele inclusive scan over the 1024 partials
    for (int o = 1; o < T; o <<= 1) {
        int x = (t >= o) ? sums[t - o] : 0;
        __syncthreads();
        sums[t] += x;
        __syncthreads();
    }
    int run = (t == 0) ? 0 : sums[t - 1];
    for (int i = begin; i < end; ++i) { off[i] = run; run += cnt[i]; }
    if (begin < n && end == n) off[n] = run;   // off[n] = total = E
}

__global__ void scatter_kernel(const int* __restrict__ src, const int* __restrict__ dst,
                               const int* __restrict__ off, int* __restrict__ fill,
                               int* __restrict__ sorted_src, int E) {
    int i = blockIdx.x * blockDim.x + threadIdx.x;
    if (i < E) {
        int d = dst[i];
        int pos = off[d] + atomicAdd(&fill[d], 1);
        sorted_src[pos] = src[i];
    }
}

// 4 waves/block, one node per wave, lane = feature channel.
__launch_bounds__(256)
__global__ void sage_kernel(const float* __restrict__ x,
                            const int* __restrict__ sorted_src,
                            const int* __restrict__ off,
                            const float* __restrict__ Wl,
                            const float* __restrict__ bl,
                            const float* __restrict__ Wr,
                            float* __restrict__ out, int N) {
    __shared__ float sWl[DFEAT * DFEAT];
    __shared__ float sWr[DFEAT * DFEAT];
    // Cooperative load of both 64x64 weight matrices (16 KB each) via float4.
    for (int i = threadIdx.x; i < DFEAT * DFEAT / 4; i += 256) {
        ((float4*)sWl)[i] = ((const float4*)Wl)[i];
        ((float4*)sWr)[i] = ((const float4*)Wr)[i];
    }
    __syncthreads();

    int wave = threadIdx.x >> 6;
    int lane = threadIdx.x & 63;
    int node = blockIdx.x * 4 + wave;
    if (node >= N) return;

    int s0 = off[node];
    int s1 = off[node + 1];
    int deg = s1 - s0;

    float acc = 0.0f;
    for (int e = s0; e < s1; ++e) {
        int s = sorted_src[e];                       // wave-uniform address
        acc += x[(size_t)s * DFEAT + lane];          // coalesced 256B row read
    }
    float mean = acc / fmaxf((float)deg, 1.0f);
    float xi = x[(size_t)node * DFEAT + lane];

    // out[node][lane] = bl[lane] + sum_k mean_k*Wl[k][lane] + xi_k*Wr[k][lane]
    float o = bl[lane];
    #pragma unroll 16
    for (int k = 0; k < DFEAT; ++k) {
        float mk = __shfl(mean, k);
        float xk = __shfl(xi, k);
        o += mk * sWl[k * DFEAT + lane] + xk * sWr[k * DFEAT + lane];
    }
    out[(size_t)node * DFEAT + lane] = o;
}

extern "C" void kernel_launch(void* const* d_in, const int* in_sizes, int n_in,
                              void* d_out, int out_size, void* d_ws, size_t ws_size,
                              hipStream_t stream) {
    const float* x  = (const float*)d_in[0];
    const int*   ei = (const int*)d_in[1];     // [2,E] flat: src then dst
    const float* Wl = (const float*)d_in[2];
    const float* bl = (const float*)d_in[3];
    const float* Wr = (const float*)d_in[4];
    float* out = (float*)d_out;

    const int N = in_sizes[0] / DFEAT;         // 100000
    const int E = in_sizes[1] / 2;             // 1600000
    const int* src = ei;
    const int* dst = ei + E;

    // Workspace layout (ints): [cnt N][fill N][off N+1][sorted_src E]
    int* ws = (int*)d_ws;
    int* cnt        = ws;
    int* fill       = ws + N;
    int* off        = ws + 2 * (size_t)N;
    int* sorted_src = ws + 3 * (size_t)N + 16;   // padded past off[N]

    // Zero cnt and fill (they're poisoned with 0xAA before every launch).
    hipMemsetAsync(cnt, 0, 2 * (size_t)N * sizeof(int), stream);

    int eb = (E + 255) / 256;
    hist_kernel<<<eb, 256, 0, stream>>>(dst, cnt, E);
    scan_kernel<<<1, 1024, 0, stream>>>(cnt, off, N);
    scatter_kernel<<<eb, 256, 0, stream>>>(src, dst, off, fill, sorted_src, E);
    sage_kernel<<<(N + 3) / 4, 256, 0, stream>>>(x, sorted_src, off, Wl, bl, Wr, out, N);
}

// Round 2
// 507.321 us; speedup vs baseline: 1.5223x; 1.5223x over previous
//
#include <hip/hip_runtime.h>

// GraphSAGEConv: out_i = mean_{j in N(i)} x_j @ W_l + b_l + x_i @ W_r
// N=100000, E=1600000, D_in=D_out=64.
//
// Pipeline: counting-sort edges by dst (int atomics only), parallel 3-kernel
// scan, then one wave per node aggregates its neighbor segment with 4-wide
// unroll (4 independent 256B row gathers in flight), GEMMs fused in-wave via
// __shfl broadcast with W_l/W_r staged in LDS.

#define DFEAT 64
#define NB_SCAN 256
#define SCAN_T 256

__global__ void hist_kernel(const int* __restrict__ dst, int* __restrict__ cnt, int E) {
    int i = blockIdx.x * blockDim.x + threadIdx.x;
    int i4 = i * 4;
    if (i4 + 3 < E) {
        int4 d = *(const int4*)&dst[i4];
        atomicAdd(&cnt[d.x], 1); atomicAdd(&cnt[d.y], 1);
        atomicAdd(&cnt[d.z], 1); atomicAdd(&cnt[d.w], 1);
    } else if (i4 < E) {
        for (int j = i4; j < E; ++j) atomicAdd(&cnt[dst[j]], 1);
    }
}

// Coalesced per-block partial sums over contiguous chunks of C counters.
__global__ void scan_partial(const int* __restrict__ cnt, int* __restrict__ bsum,
                             int N, int C) {
    __shared__ int red[SCAN_T];
    int b = blockIdx.x, t = threadIdx.x;
    int lo = b * C;
    int hi = lo + C; if (hi > N) hi = N;
    int s = 0;
    for (int i = lo + t; i < hi; i += SCAN_T) s += cnt[i];
    red[t] = s; __syncthreads();
    for (int o = SCAN_T / 2; o > 0; o >>= 1) {
        if (t < o) red[t] += red[t + o];
        __syncthreads();
    }
    if (t == 0) bsum[b] = red[0];
}

// Single block: exclusive scan of the 256 block sums; also writes off[N]=E.
__global__ void scan_bsum(const int* __restrict__ bsum, int* __restrict__ bbase,
                          int* __restrict__ offN) {
    __shared__ int a[NB_SCAN], b[NB_SCAN];
    int t = threadIdx.x;
    a[t] = bsum[t]; __syncthreads();
    int* s = a; int* d = b;
    for (int o = 1; o < NB_SCAN; o <<= 1) {
        d[t] = s[t] + (t >= o ? s[t - o] : 0);
        __syncthreads();
        int* tmp = s; s = d; d = tmp;
    }
    bbase[t] = (t == 0) ? 0 : s[t - 1];
    if (t == NB_SCAN - 1) *offN = s[t];
}

// Per-block local exclusive scan of its chunk + bbase, coalesced write of off.
__global__ void scan_write(const int* __restrict__ cnt, const int* __restrict__ bbase,
                           int* __restrict__ off, int N, int C) {
    __shared__ int buf[2][512];                 // C <= 512
    int b = blockIdx.x, t = threadIdx.x;
    int lo = b * C;
    for (int i = t; i < 512; i += SCAN_T)
        buf[0][i] = (i < C && lo + i < N) ? cnt[lo + i] : 0;
    __syncthreads();
    int cur = 0;
    for (int o = 1; o < 512; o <<= 1) {
        for (int i = t; i < 512; i += SCAN_T)
            buf[cur ^ 1][i] = buf[cur][i] + (i >= o ? buf[cur][i - o] : 0);
        cur ^= 1;
        __syncthreads();
    }
    int base = bbase[b];
    for (int i = t; i < 512; i += SCAN_T) {
        int idx = lo + i;
        if (i < C && idx < N)
            off[idx] = base + (i == 0 ? 0 : buf[cur][i - 1]);
    }
}

__global__ void scatter_kernel(const int* __restrict__ src, const int* __restrict__ dst,
                               const int* __restrict__ off, int* __restrict__ cnt,
                               int* __restrict__ sorted_src, int E) {
    int i = blockIdx.x * blockDim.x + threadIdx.x;
    if (i < E) {
        int d = dst[i];
        int pos = off[d] + atomicSub(&cnt[d], 1) - 1;
        sorted_src[pos] = src[i];
    }
}

// 4 waves/block, one node per wave, lane = feature channel.
__launch_bounds__(256)
__global__ void sage_kernel(const float* __restrict__ x,
                            const int* __restrict__ sorted_src,
                            const int* __restrict__ off,
                            const float* __restrict__ Wl,
                            const float* __restrict__ bl,
                            const float* __restrict__ Wr,
                            float* __restrict__ out, int N) {
    __shared__ float sWl[DFEAT * DFEAT];
    __shared__ float sWr[DFEAT * DFEAT];
    for (int i = threadIdx.x; i < DFEAT * DFEAT / 4; i += 256) {
        ((float4*)sWl)[i] = ((const float4*)Wl)[i];
        ((float4*)sWr)[i] = ((const float4*)Wr)[i];
    }
    __syncthreads();

    int wave = threadIdx.x >> 6;
    int lane = threadIdx.x & 63;
    int node = blockIdx.x * 4 + wave;
    if (node >= N) return;

    int s0 = off[node];
    int s1 = off[node + 1];
    int deg = s1 - s0;

    // 4 independent accumulators -> 4 row gathers in flight per iteration.
    float acc0 = 0.f, acc1 = 0.f, acc2 = 0.f, acc3 = 0.f;
    int e = s0;
    for (; e + 4 <= s1; e += 4) {
        int i0 = sorted_src[e];
        int i1 = sorted_src[e + 1];
        int i2 = sorted_src[e + 2];
        int i3 = sorted_src[e + 3];
        float a0 = x[(size_t)i0 * DFEAT + lane];
        float a1 = x[(size_t)i1 * DFEAT + lane];
        float a2 = x[(size_t)i2 * DFEAT + lane];
        float a3 = x[(size_t)i3 * DFEAT + lane];
        acc0 += a0; acc1 += a1; acc2 += a2; acc3 += a3;
    }
    for (; e < s1; ++e) acc0 += x[(size_t)sorted_src[e] * DFEAT + lane];

    float mean = ((acc0 + acc1) + (acc2 + acc3)) / fmaxf((float)deg, 1.0f);
    float xi = x[(size_t)node * DFEAT + lane];

    // out[node][lane] = bl[lane] + sum_k mean_k*Wl[k][lane] + xi_k*Wr[k][lane]
    float o = bl[lane];
    #pragma unroll 16
    for (int k = 0; k < DFEAT; ++k) {
        float mk = __shfl(mean, k);
        float xk = __shfl(xi, k);
        o += mk * sWl[k * DFEAT + lane] + xk * sWr[k * DFEAT + lane];
    }
    out[(size_t)node * DFEAT + lane] = o;
}

extern "C" void kernel_launch(void* const* d_in, const int* in_sizes, int n_in,
                              void* d_out, int out_size, void* d_ws, size_t ws_size,
                              hipStream_t stream) {
    const float* x  = (const float*)d_in[0];
    const int*   ei = (const int*)d_in[1];     // [2,E] flat: src then dst
    const float* Wl = (const float*)d_in[2];
    const float* bl = (const float*)d_in[3];
    const float* Wr = (const float*)d_in[4];
    float* out = (float*)d_out;

    const int N = in_sizes[0] / DFEAT;         // 100000
    const int E = in_sizes[1] / 2;             // 1600000
    const int* src = ei;
    const int* dst = ei + E;

    const int C = (N + NB_SCAN - 1) / NB_SCAN; // 391 (<= 512)

    // Workspace layout (ints): [cnt N][off N+1 ..pad][bsum 256][bbase 256][sorted_src E]
    int* ws = (int*)d_ws;
    int* cnt        = ws;
    int* off        = ws + N;
    int* bsum       = ws + 2 * (size_t)N + 16;
    int* bbase      = bsum + NB_SCAN;
    int* sorted_src = bbase + NB_SCAN;

    hipMemsetAsync(cnt, 0, (size_t)N * sizeof(int), stream);

    hist_kernel<<<(E / 4 + 255) / 256, 256, 0, stream>>>(dst, cnt, E);
    scan_partial<<<NB_SCAN, SCAN_T, 0, stream>>>(cnt, bsum, N, C);
    scan_bsum<<<1, NB_SCAN, 0, stream>>>(bsum, bbase, off + N);
    scan_write<<<NB_SCAN, SCAN_T, 0, stream>>>(cnt, bbase, off, N, C);
    scatter_kernel<<<(E + 255) / 256, 256, 0, stream>>>(src, dst, off, cnt, sorted_src, E);
    sage_kernel<<<(N + 3) / 4, 256, 0, stream>>>(x, sorted_src, off, Wl, bl, Wr, out, N);
}

// Round 3
// 466.991 us; speedup vs baseline: 1.6537x; 1.0864x over previous
//
#include <hip/hip_runtime.h>

// GraphSAGEConv: out_i = mean_{j in N(i)} x_j @ W_l + b_l + x_i @ W_r
// N=100000, E=1600000, D_in=D_out=64.
//
// Pipeline: counting-sort edges by dst (int atomics only), parallel 3-kernel
// scan, bf16 copy of x, then one wave per node: coalesced preload of the
// node's neighbor indices (1 load for <=64 edges), 8 independent 128B bf16
// row gathers in flight, mean in f32, 64x64 GEMMs fused in-wave via __shfl
// with bf16 weights staged in 16KB LDS.

#define DFEAT 64
#define NB_SCAN 256
#define SCAN_T 256

static __device__ __forceinline__ unsigned short f2bf(float f) {
    unsigned int u = __float_as_uint(f);
    unsigned int r = (u + 0x7FFFu + ((u >> 16) & 1u)) >> 16;   // RNE
    return (unsigned short)r;
}
static __device__ __forceinline__ float bf2f(unsigned short h) {
    return __uint_as_float(((unsigned int)h) << 16);
}

__global__ void hist_kernel(const int* __restrict__ dst, int* __restrict__ cnt, int E) {
    int i = blockIdx.x * blockDim.x + threadIdx.x;
    int i4 = i * 4;
    if (i4 + 3 < E) {
        int4 d = *(const int4*)&dst[i4];
        atomicAdd(&cnt[d.x], 1); atomicAdd(&cnt[d.y], 1);
        atomicAdd(&cnt[d.z], 1); atomicAdd(&cnt[d.w], 1);
    } else if (i4 < E) {
        for (int j = i4; j < E; ++j) atomicAdd(&cnt[dst[j]], 1);
    }
}

// Convert x (nx4 float4 units) + Wl + Wr (1024 float4 units each) to bf16.
__global__ void convert_kernel(const float* __restrict__ x,
                               const float* __restrict__ Wl,
                               const float* __restrict__ Wr,
                               unsigned short* __restrict__ xh,
                               unsigned short* __restrict__ wl16,
                               unsigned short* __restrict__ wr16,
                               int nx4, int do_x) {
    int i = blockIdx.x * blockDim.x + threadIdx.x;
    const float* sp; unsigned short* dp; int k;
    if (i < 1024)      { sp = Wl; dp = wl16; k = i; }
    else if (i < 2048) { sp = Wr; dp = wr16; k = i - 1024; }
    else if (do_x && i - 2048 < nx4) { sp = x; dp = xh; k = i - 2048; }
    else return;
    float4 v = ((const float4*)sp)[k];
    ushort4 h;
    h.x = f2bf(v.x); h.y = f2bf(v.y); h.z = f2bf(v.z); h.w = f2bf(v.w);
    ((ushort4*)dp)[k] = h;
}

// Coalesced per-block partial sums over contiguous chunks of C counters.
__global__ void scan_partial(const int* __restrict__ cnt, int* __restrict__ bsum,
                             int N, int C) {
    __shared__ int red[SCAN_T];
    int b = blockIdx.x, t = threadIdx.x;
    int lo = b * C;
    int hi = lo + C; if (hi > N) hi = N;
    int s = 0;
    for (int i = lo + t; i < hi; i += SCAN_T) s += cnt[i];
    red[t] = s; __syncthreads();
    for (int o = SCAN_T / 2; o > 0; o >>= 1) {
        if (t < o) red[t] += red[t + o];
        __syncthreads();
    }
    if (t == 0) bsum[b] = red[0];
}

__global__ void scan_bsum(const int* __restrict__ bsum, int* __restrict__ bbase,
                          int* __restrict__ offN) {
    __shared__ int a[NB_SCAN], b[NB_SCAN];
    int t = threadIdx.x;
    a[t] = bsum[t]; __syncthreads();
    int* s = a; int* d = b;
    for (int o = 1; o < NB_SCAN; o <<= 1) {
        d[t] = s[t] + (t >= o ? s[t - o] : 0);
        __syncthreads();
        int* tmp = s; s = d; d = tmp;
    }
    bbase[t] = (t == 0) ? 0 : s[t - 1];
    if (t == NB_SCAN - 1) *offN = s[t];
}

__global__ void scan_write(const int* __restrict__ cnt, const int* __restrict__ bbase,
                           int* __restrict__ off, int N, int C) {
    __shared__ int buf[2][512];                 // C <= 512
    int b = blockIdx.x, t = threadIdx.x;
    int lo = b * C;
    for (int i = t; i < 512; i += SCAN_T)
        buf[0][i] = (i < C && lo + i < N) ? cnt[lo + i] : 0;
    __syncthreads();
    int cur = 0;
    for (int o = 1; o < 512; o <<= 1) {
        for (int i = t; i < 512; i += SCAN_T)
            buf[cur ^ 1][i] = buf[cur][i] + (i >= o ? buf[cur][i - o] : 0);
        cur ^= 1;
        __syncthreads();
    }
    int base = bbase[b];
    for (int i = t; i < 512; i += SCAN_T) {
        int idx = lo + i;
        if (i < C && idx < N)
            off[idx] = base + (i == 0 ? 0 : buf[cur][i - 1]);
    }
}

__global__ void scatter_kernel(const int* __restrict__ src, const int* __restrict__ dst,
                               const int* __restrict__ off, int* __restrict__ cnt,
                               int* __restrict__ sorted_src, int E) {
    int i = blockIdx.x * blockDim.x + threadIdx.x;
    if (i < E) {
        int d = dst[i];
        int pos = off[d] + atomicSub(&cnt[d], 1) - 1;
        sorted_src[pos] = src[i];
    }
}

// 4 waves/block, one node per wave, lane = feature channel.
// USE_BF16: gather neighbor rows from the bf16 copy of x (half the bytes).
template <bool USE_BF16>
__launch_bounds__(256, 6)
__global__ void sage_kernel(const float* __restrict__ x,
                            const unsigned short* __restrict__ xh,
                            const int* __restrict__ sorted_src,
                            const int* __restrict__ off,
                            const unsigned short* __restrict__ wl16,
                            const unsigned short* __restrict__ wr16,
                            const float* __restrict__ bl,
                            float* __restrict__ out, int N) {
    __shared__ unsigned short sWl[DFEAT * DFEAT];   // 8 KB
    __shared__ unsigned short sWr[DFEAT * DFEAT];   // 8 KB
    for (int i = threadIdx.x; i < DFEAT * DFEAT / 8; i += 256) {
        ((uint4*)sWl)[i] = ((const uint4*)wl16)[i];
        ((uint4*)sWr)[i] = ((const uint4*)wr16)[i];
    }
    __syncthreads();

    int wave = threadIdx.x >> 6;
    int lane = threadIdx.x & 63;
    int node = blockIdx.x * 4 + wave;
    if (node >= N) return;

    int s0 = off[node];
    int s1 = off[node + 1];
    int deg = s1 - s0;

    float acc0 = 0.f, acc1 = 0.f, acc2 = 0.f, acc3 = 0.f;
    float acc4 = 0.f, acc5 = 0.f, acc6 = 0.f, acc7 = 0.f;

    for (int base = s0; base < s1; base += 64) {
        int cc = s1 - base; if (cc > 64) cc = 64;
        // One coalesced load grabs this chunk's neighbor indices.
        int myidx = (lane < cc) ? sorted_src[base + lane] : 0;

        int j = 0;
        for (; j + 8 <= cc; j += 8) {
            int i0 = __shfl(myidx, j + 0);
            int i1 = __shfl(myidx, j + 1);
            int i2 = __shfl(myidx, j + 2);
            int i3 = __shfl(myidx, j + 3);
            int i4 = __shfl(myidx, j + 4);
            int i5 = __shfl(myidx, j + 5);
            int i6 = __shfl(myidx, j + 6);
            int i7 = __shfl(myidx, j + 7);
            if (USE_BF16) {
                float a0 = bf2f(xh[(size_t)i0 * DFEAT + lane]);
                float a1 = bf2f(xh[(size_t)i1 * DFEAT + lane]);
                float a2 = bf2f(xh[(size_t)i2 * DFEAT + lane]);
                float a3 = bf2f(xh[(size_t)i3 * DFEAT + lane]);
                float a4 = bf2f(xh[(size_t)i4 * DFEAT + lane]);
                float a5 = bf2f(xh[(size_t)i5 * DFEAT + lane]);
                float a6 = bf2f(xh[(size_t)i6 * DFEAT + lane]);
                float a7 = bf2f(xh[(size_t)i7 * DFEAT + lane]);
                acc0 += a0; acc1 += a1; acc2 += a2; acc3 += a3;
                acc4 += a4; acc5 += a5; acc6 += a6; acc7 += a7;
            } else {
                acc0 += x[(size_t)i0 * DFEAT + lane];
                acc1 += x[(size_t)i1 * DFEAT + lane];
                acc2 += x[(size_t)i2 * DFEAT + lane];
                acc3 += x[(size_t)i3 * DFEAT + lane];
                acc4 += x[(size_t)i4 * DFEAT + lane];
                acc5 += x[(size_t)i5 * DFEAT + lane];
                acc6 += x[(size_t)i6 * DFEAT + lane];
                acc7 += x[(size_t)i7 * DFEAT + lane];
            }
        }
        for (; j < cc; ++j) {
            int id = __shfl(myidx, j);
            if (USE_BF16) acc0 += bf2f(xh[(size_t)id * DFEAT + lane]);
            else          acc0 += x[(size_t)id * DFEAT + lane];
        }
    }

    float mean = (((acc0 + acc1) + (acc2 + acc3)) + ((acc4 + acc5) + (acc6 + acc7)))
                 / fmaxf((float)deg, 1.0f);
    float xi = x[(size_t)node * DFEAT + lane];

    float o = bl[lane];
    #pragma unroll
    for (int k = 0; k < DFEAT; ++k) {
        float mk = __shfl(mean, k);
        float xk = __shfl(xi, k);
        o += mk * bf2f(sWl[k * DFEAT + lane]) + xk * bf2f(sWr[k * DFEAT + lane]);
    }
    out[(size_t)node * DFEAT + lane] = o;
}

extern "C" void kernel_launch(void* const* d_in, const int* in_sizes, int n_in,
                              void* d_out, int out_size, void* d_ws, size_t ws_size,
                              hipStream_t stream) {
    const float* x  = (const float*)d_in[0];
    const int*   ei = (const int*)d_in[1];     // [2,E] flat: src then dst
    const float* Wl = (const float*)d_in[2];
    const float* bl = (const float*)d_in[3];
    const float* Wr = (const float*)d_in[4];
    float* out = (float*)d_out;

    const int N = in_sizes[0] / DFEAT;         // 100000
    const int E = in_sizes[1] / 2;             // 1600000
    const int* src = ei;
    const int* dst = ei + E;

    const int C = (N + NB_SCAN - 1) / NB_SCAN; // 391 (<= 512)

    // Workspace (all offsets stay 16B-aligned):
    // [cnt N][off N+16][bsum 256][bbase 256][sorted_src E][wl16 4096][wr16 4096][xh N*64]
    int* ws = (int*)d_ws;
    int* cnt        = ws;
    int* off        = cnt + N;
    int* bsum       = off + N + 16;
    int* bbase      = bsum + NB_SCAN;
    int* sorted_src = bbase + NB_SCAN;
    unsigned short* wl16 = (unsigned short*)(sorted_src + E);
    unsigned short* wr16 = wl16 + DFEAT * DFEAT;
    unsigned short* xh   = wr16 + DFEAT * DFEAT;

    size_t base_bytes = (size_t)(3 * N + 16 + 2 * NB_SCAN + E) * 4 + 2 * DFEAT * DFEAT * 2;
    int use_bf16 = (ws_size >= base_bytes + (size_t)N * DFEAT * 2) ? 1 : 0;

    hipMemsetAsync(cnt, 0, (size_t)N * sizeof(int), stream);

    int nx4 = N * DFEAT / 4;
    int conv_threads = 2048 + (use_bf16 ? nx4 : 0);
    convert_kernel<<<(conv_threads + 255) / 256, 256, 0, stream>>>(
        x, Wl, Wr, xh, wl16, wr16, nx4, use_bf16);

    hist_kernel<<<(E / 4 + 255) / 256, 256, 0, stream>>>(dst, cnt, E);
    scan_partial<<<NB_SCAN, SCAN_T, 0, stream>>>(cnt, bsum, N, C);
    scan_bsum<<<1, NB_SCAN, 0, stream>>>(bsum, bbase, off + N);
    scan_write<<<NB_SCAN, SCAN_T, 0, stream>>>(cnt, bbase, off, N, C);
    scatter_kernel<<<(E + 255) / 256, 256, 0, stream>>>(src, dst, off, cnt, sorted_src, E);

    if (use_bf16)
        sage_kernel<true><<<(N + 3) / 4, 256, 0, stream>>>(
            x, xh, sorted_src, off, wl16, wr16, bl, out, N);
    else
        sage_kernel<false><<<(N + 3) / 4, 256, 0, stream>>>(
            x, xh, sorted_src, off, wl16, wr16, bl, out, N);
}

// Round 4
// 323.090 us; speedup vs baseline: 2.3903x; 1.4454x over previous
//
#include <hip/hip_runtime.h>

// GraphSAGEConv: out_i = mean_{j in N(i)} x_j @ W_l + b_l + x_i @ W_r
// N=100000, E=1600000, D_in=D_out=64.
//
// Pipeline:
//   convert: x -> bf16 table xh, Wl/Wr -> bf16
//   counting-sort edges by dst (hist + 3-kernel scan + scatter)
//   agg_kernel: one wave per node, 2 edges per load instr (half-wave x ushort2),
//               16 rows in flight; writes f32 mean rows into d_out (scratch).
//   gemm_kernel: out = [mean|x]_bf16 @ [Wl;Wr]_bf16 + b via mfma_f32_16x16x32_bf16,
//                16-node tiles; reads its own tile rows from d_out then overwrites.

#define DFEAT 64
#define NB_SCAN 256
#define SCAN_T 256

typedef short bf16x8 __attribute__((ext_vector_type(8)));
typedef float f32x4 __attribute__((ext_vector_type(4)));

static __device__ __forceinline__ unsigned short f2bf(float f) {
    unsigned int u = __float_as_uint(f);
    unsigned int r = (u + 0x7FFFu + ((u >> 16) & 1u)) >> 16;   // RNE
    return (unsigned short)r;
}
static __device__ __forceinline__ float bf2f_lo(unsigned int u) {
    return __uint_as_float(u << 16);
}
static __device__ __forceinline__ float bf2f_hi(unsigned int u) {
    return __uint_as_float(u & 0xFFFF0000u);
}

__global__ void hist_kernel(const int* __restrict__ dst, int* __restrict__ cnt, int E) {
    int i = blockIdx.x * blockDim.x + threadIdx.x;
    int i4 = i * 4;
    if (i4 + 3 < E) {
        int4 d = *(const int4*)&dst[i4];
        atomicAdd(&cnt[d.x], 1); atomicAdd(&cnt[d.y], 1);
        atomicAdd(&cnt[d.z], 1); atomicAdd(&cnt[d.w], 1);
    } else if (i4 < E) {
        for (int j = i4; j < E; ++j) atomicAdd(&cnt[dst[j]], 1);
    }
}

// Convert x (nx4 float4 units) + Wl + Wr (1024 float4 units each) to bf16.
__global__ void convert_kernel(const float* __restrict__ x,
                               const float* __restrict__ Wl,
                               const float* __restrict__ Wr,
                               unsigned short* __restrict__ xh,
                               unsigned short* __restrict__ wl16,
                               unsigned short* __restrict__ wr16,
                               int nx4) {
    int i = blockIdx.x * blockDim.x + threadIdx.x;
    const float* sp; unsigned short* dp; int k;
    if (i < 1024)      { sp = Wl; dp = wl16; k = i; }
    else if (i < 2048) { sp = Wr; dp = wr16; k = i - 1024; }
    else if (i - 2048 < nx4) { sp = x; dp = xh; k = i - 2048; }
    else return;
    float4 v = ((const float4*)sp)[k];
    ushort4 h;
    h.x = f2bf(v.x); h.y = f2bf(v.y); h.z = f2bf(v.z); h.w = f2bf(v.w);
    ((ushort4*)dp)[k] = h;
}

__global__ void scan_partial(const int* __restrict__ cnt, int* __restrict__ bsum,
                             int N, int C) {
    __shared__ int red[SCAN_T];
    int b = blockIdx.x, t = threadIdx.x;
    int lo = b * C;
    int hi = lo + C; if (hi > N) hi = N;
    int s = 0;
    for (int i = lo + t; i < hi; i += SCAN_T) s += cnt[i];
    red[t] = s; __syncthreads();
    for (int o = SCAN_T / 2; o > 0; o >>= 1) {
        if (t < o) red[t] += red[t + o];
        __syncthreads();
    }
    if (t == 0) bsum[b] = red[0];
}

__global__ void scan_bsum(const int* __restrict__ bsum, int* __restrict__ bbase,
                          int* __restrict__ offN) {
    __shared__ int a[NB_SCAN], b[NB_SCAN];
    int t = threadIdx.x;
    a[t] = bsum[t]; __syncthreads();
    int* s = a; int* d = b;
    for (int o = 1; o < NB_SCAN; o <<= 1) {
        d[t] = s[t] + (t >= o ? s[t - o] : 0);
        __syncthreads();
        int* tmp = s; s = d; d = tmp;
    }
    bbase[t] = (t == 0) ? 0 : s[t - 1];
    if (t == NB_SCAN - 1) *offN = s[t];
}

__global__ void scan_write(const int* __restrict__ cnt, const int* __restrict__ bbase,
                           int* __restrict__ off, int N, int C) {
    __shared__ int buf[2][512];                 // C <= 512
    int b = blockIdx.x, t = threadIdx.x;
    int lo = b * C;
    for (int i = t; i < 512; i += SCAN_T)
        buf[0][i] = (i < C && lo + i < N) ? cnt[lo + i] : 0;
    __syncthreads();
    int cur = 0;
    for (int o = 1; o < 512; o <<= 1) {
        for (int i = t; i < 512; i += SCAN_T)
            buf[cur ^ 1][i] = buf[cur][i] + (i >= o ? buf[cur][i - o] : 0);
        cur ^= 1;
        __syncthreads();
    }
    int base = bbase[b];
    for (int i = t; i < 512; i += SCAN_T) {
        int idx = lo + i;
        if (i < C && idx < N)
            off[idx] = base + (i == 0 ? 0 : buf[cur][i - 1]);
    }
}

__global__ void scatter_kernel(const int* __restrict__ src, const int* __restrict__ dst,
                               const int* __restrict__ off, int* __restrict__ cnt,
                               int* __restrict__ sorted_src, int E) {
    int i = blockIdx.x * blockDim.x + threadIdx.x;
    if (i < E) {
        int d = dst[i];
        int pos = off[d] + atomicSub(&cnt[d], 1) - 1;
        sorted_src[pos] = src[i];
    }
}

// One wave per node. Lanes 0-31 handle even edges, 32-63 odd edges: each
// load instruction gathers TWO 128B bf16 rows (ushort2/lane). 8-deep unroll
// = 16 rows in flight. Writes f32 mean row into mean_out (= d_out scratch).
__launch_bounds__(256)
__global__ void agg_kernel(const unsigned short* __restrict__ xh,
                           const int* __restrict__ sorted_src,
                           const int* __restrict__ off,
                           float* __restrict__ mean_out, int N) {
    int wave = threadIdx.x >> 6;
    int lane = threadIdx.x & 63;
    int node = blockIdx.x * 4 + wave;
    if (node >= N) return;

    int s0 = off[node];
    int s1 = off[node + 1];
    int deg = s1 - s0;
    int half = lane >> 5;          // which edge of the pair
    int l2 = lane & 31;            // channel pair index

    float2 acc[8];
    #pragma unroll
    for (int u = 0; u < 8; ++u) { acc[u].x = 0.f; acc[u].y = 0.f; }

    for (int base = s0; base < s1; base += 64) {
        int cc = s1 - base; if (cc > 64) cc = 64;
        int myidx = (lane < cc) ? sorted_src[base + lane] : 0;
        int pairs = cc >> 1;
        int s = 0;
        for (; s + 8 <= pairs; s += 8) {
            unsigned int vv[8];
            #pragma unroll
            for (int u = 0; u < 8; ++u) {
                int id = __shfl(myidx, 2 * (s + u) + half);
                vv[u] = *(const unsigned int*)(xh + (size_t)id * DFEAT + l2 * 2);
            }
            #pragma unroll
            for (int u = 0; u < 8; ++u) {
                acc[u].x += bf2f_lo(vv[u]);
                acc[u].y += bf2f_hi(vv[u]);
            }
        }
        for (; s < pairs; ++s) {
            int id = __shfl(myidx, 2 * s + half);
            unsigned int v = *(const unsigned int*)(xh + (size_t)id * DFEAT + l2 * 2);
            acc[0].x += bf2f_lo(v);
            acc[0].y += bf2f_hi(v);
        }
        if (cc & 1) {
            int id = __shfl(myidx, cc - 1);
            unsigned int v = *(const unsigned int*)(xh + (size_t)id * DFEAT + l2 * 2);
            if (half == 0) {               // only even half adds the odd edge
                acc[1].x += bf2f_lo(v);
                acc[1].y += bf2f_hi(v);
            }
        }
    }

    float2 t;
    t.x = ((acc[0].x + acc[1].x) + (acc[2].x + acc[3].x))
        + ((acc[4].x + acc[5].x) + (acc[6].x + acc[7].x));
    t.y = ((acc[0].y + acc[1].y) + (acc[2].y + acc[3].y))
        + ((acc[4].y + acc[5].y) + (acc[6].y + acc[7].y));
    t.x += __shfl_xor(t.x, 32);
    t.y += __shfl_xor(t.y, 32);

    float inv = 1.0f / fmaxf((float)deg, 1.0f);
    if (lane < 32) {
        float2 m; m.x = t.x * inv; m.y = t.y * inv;
        ((float2*)mean_out)[(size_t)node * 32 + l2] = m;
    }
}

// out = [mean | x]_bf16 @ [Wl ; Wr]_bf16 + b, 16-node tiles per wave.
// A-frag:  A[m = lane&15][k = quad*8 + j];  B-frag: B[k = quad*8 + j][n = lane&15]
// C/D:     col = lane&15, row = quad*4 + reg.
__launch_bounds__(256)
__global__ void gemm_kernel(const float* __restrict__ meanf,    // == out (scratch)
                            const unsigned short* __restrict__ xh,
                            const unsigned short* __restrict__ wl16,
                            const unsigned short* __restrict__ wr16,
                            const float* __restrict__ bl,
                            float* __restrict__ out, int N, int ntiles) {
    int lane = threadIdx.x & 63;
    int n15 = lane & 15;
    int quad = lane >> 4;
    int wid = (blockIdx.x * blockDim.x + threadIdx.x) >> 6;
    int nwaves = (gridDim.x * blockDim.x) >> 6;

    // Build all 16 B-fragments once per wave (loop-invariant weights).
    bf16x8 bfrag[4][4];
    #pragma unroll
    for (int kk = 0; kk < 4; ++kk) {
        const unsigned short* W = (kk < 2) ? wl16 : wr16;
        int kbase = (kk & 1) * 32 + quad * 8;
        #pragma unroll
        for (int nt = 0; nt < 4; ++nt) {
            #pragma unroll
            for (int j = 0; j < 8; ++j)
                bfrag[kk][nt][j] = (short)W[(kbase + j) * DFEAT + nt * 16 + n15];
        }
    }
    float bias[4];
    #pragma unroll
    for (int nt = 0; nt < 4; ++nt) bias[nt] = bl[nt * 16 + n15];

    for (int t = wid; t < ntiles; t += nwaves) {
        int n0 = t * 16;
        int row = n0 + n15; if (row >= N) row = N - 1;

        bf16x8 afrag[4];
        // k = 0..63: mean path (f32 rows in d_out scratch -> bf16)
        #pragma unroll
        for (int kk = 0; kk < 2; ++kk) {
            const float* p = meanf + (size_t)row * DFEAT + kk * 32 + quad * 8;
            float4 lo = *(const float4*)p;
            float4 hi = *(const float4*)(p + 4);
            afrag[kk][0] = (short)f2bf(lo.x); afrag[kk][1] = (short)f2bf(lo.y);
            afrag[kk][2] = (short)f2bf(lo.z); afrag[kk][3] = (short)f2bf(lo.w);
            afrag[kk][4] = (short)f2bf(hi.x); afrag[kk][5] = (short)f2bf(hi.y);
            afrag[kk][6] = (short)f2bf(hi.z); afrag[kk][7] = (short)f2bf(hi.w);
        }
        // k = 64..127: root path (bf16 rows, direct 16B loads)
        #pragma unroll
        for (int kk = 0; kk < 2; ++kk)
            afrag[2 + kk] = *(const bf16x8*)(xh + (size_t)row * DFEAT + kk * 32 + quad * 8);

        #pragma unroll
        for (int nt = 0; nt < 4; ++nt) {
            f32x4 c = {0.f, 0.f, 0.f, 0.f};
            #pragma unroll
            for (int kk = 0; kk < 4; ++kk)
                c = __builtin_amdgcn_mfma_f32_16x16x32_bf16(afrag[kk], bfrag[kk][nt], c, 0, 0, 0);
            #pragma unroll
            for (int r = 0; r < 4; ++r) {
                int orow = n0 + quad * 4 + r;
                if (orow < N)
                    out[(size_t)orow * DFEAT + nt * 16 + n15] = c[r] + bias[nt];
            }
        }
    }
}

extern "C" void kernel_launch(void* const* d_in, const int* in_sizes, int n_in,
                              void* d_out, int out_size, void* d_ws, size_t ws_size,
                              hipStream_t stream) {
    const float* x  = (const float*)d_in[0];
    const int*   ei = (const int*)d_in[1];     // [2,E] flat: src then dst
    const float* Wl = (const float*)d_in[2];
    const float* bl = (const float*)d_in[3];
    const float* Wr = (const float*)d_in[4];
    float* out = (float*)d_out;

    const int N = in_sizes[0] / DFEAT;         // 100000
    const int E = in_sizes[1] / 2;             // 1600000
    const int* src = ei;
    const int* dst = ei + E;

    const int C = (N + NB_SCAN - 1) / NB_SCAN; // 391 (<= 512)

    // Workspace: [cnt N][off N+16][bsum 256][bbase 256][sorted_src E][wl16][wr16][xh N*64]
    int* ws = (int*)d_ws;
    int* cnt        = ws;
    int* off        = cnt + N;
    int* bsum       = off + N + 16;
    int* bbase      = bsum + NB_SCAN;
    int* sorted_src = bbase + NB_SCAN;
    unsigned short* wl16 = (unsigned short*)(sorted_src + E);
    unsigned short* wr16 = wl16 + DFEAT * DFEAT;
    unsigned short* xh   = wr16 + DFEAT * DFEAT;

    hipMemsetAsync(cnt, 0, (size_t)N * sizeof(int), stream);

    int nx4 = N * DFEAT / 4;
    convert_kernel<<<(2048 + nx4 + 255) / 256, 256, 0, stream>>>(
        x, Wl, Wr, xh, wl16, wr16, nx4);

    hist_kernel<<<(E / 4 + 255) / 256, 256, 0, stream>>>(dst, cnt, E);
    scan_partial<<<NB_SCAN, SCAN_T, 0, stream>>>(cnt, bsum, N, C);
    scan_bsum<<<1, NB_SCAN, 0, stream>>>(bsum, bbase, off + N);
    scan_write<<<NB_SCAN, SCAN_T, 0, stream>>>(cnt, bbase, off, N, C);
    scatter_kernel<<<(E + 255) / 256, 256, 0, stream>>>(src, dst, off, cnt, sorted_src, E);

    // mean rows -> d_out (scratch); gemm reads its own tile rows then overwrites.
    agg_kernel<<<(N + 3) / 4, 256, 0, stream>>>(xh, sorted_src, off, out, N);

    int ntiles = (N + 15) / 16;                // 6250
    gemm_kernel<<<400, 256, 0, stream>>>(out, xh, wl16, wr16, bl, out, N, ntiles);
}

// Round 5
// 266.827 us; speedup vs baseline: 2.8943x; 1.2109x over previous
//
#include <hip/hip_runtime.h>

// GraphSAGEConv: out_i = mean_{j in N(i)} x_j @ W_l + b_l + x_i @ W_r
// N=100000, E=1600000, D_in=D_out=64.
//
// Pipeline:
//   convert: x -> bf16 table xh, Wl/Wr -> bf16
//   hist + 3-kernel scan -> CSR off[]
//   binpass:  2-level binned sort, pass 1 — per-block LDS histogram over
//             coarse buckets (256 nodes), space reserved per (block,bucket),
//             edges packed (src<<8)|(dst&255) written to the bucket's
//             contiguous region of a staging array in d_out. Writes fill
//             whole 64B lines (kills the 16x write amplification scatter had).
//   sortpass: pass 2 — one block per bucket, coalesced read of its region,
//             per-node position via LDS counters + off, clustered writes of
//             sorted_src.
//   agg_kernel: one wave per node, 2 edges per load instr (half-wave x
//             ushort2), 16 bf16 rows in flight; writes f32 mean rows into
//             d_out (overwrites staging — staging fully consumed by then).
//   gemm_kernel: out = [mean|x]_bf16 @ [Wl;Wr]_bf16 + b via
//             mfma_f32_16x16x32_bf16, 16-node tiles, in-place over d_out.

#define DFEAT 64
#define NB_SCAN 256
#define SCAN_T 256
#define BSHIFT 8                     // 256 nodes per coarse bucket
#define MAXBUCK 512                  // supports N <= 131072

typedef short bf16x8 __attribute__((ext_vector_type(8)));
typedef float f32x4 __attribute__((ext_vector_type(4)));

static __device__ __forceinline__ unsigned short f2bf(float f) {
    unsigned int u = __float_as_uint(f);
    unsigned int r = (u + 0x7FFFu + ((u >> 16) & 1u)) >> 16;   // RNE
    return (unsigned short)r;
}
static __device__ __forceinline__ float bf2f_lo(unsigned int u) {
    return __uint_as_float(u << 16);
}
static __device__ __forceinline__ float bf2f_hi(unsigned int u) {
    return __uint_as_float(u & 0xFFFF0000u);
}

__global__ void hist_kernel(const int* __restrict__ dst, int* __restrict__ cnt, int E) {
    int i = blockIdx.x * blockDim.x + threadIdx.x;
    int i4 = i * 4;
    if (i4 + 3 < E) {
        int4 d = *(const int4*)&dst[i4];
        atomicAdd(&cnt[d.x], 1); atomicAdd(&cnt[d.y], 1);
        atomicAdd(&cnt[d.z], 1); atomicAdd(&cnt[d.w], 1);
    } else if (i4 < E) {
        for (int j = i4; j < E; ++j) atomicAdd(&cnt[dst[j]], 1);
    }
}

__global__ void convert_kernel(const float* __restrict__ x,
                               const float* __restrict__ Wl,
                               const float* __restrict__ Wr,
                               unsigned short* __restrict__ xh,
                               unsigned short* __restrict__ wl16,
                               unsigned short* __restrict__ wr16,
                               int nx4) {
    int i = blockIdx.x * blockDim.x + threadIdx.x;
    const float* sp; unsigned short* dp; int k;
    if (i < 1024)      { sp = Wl; dp = wl16; k = i; }
    else if (i < 2048) { sp = Wr; dp = wr16; k = i - 1024; }
    else if (i - 2048 < nx4) { sp = x; dp = xh; k = i - 2048; }
    else return;
    float4 v = ((const float4*)sp)[k];
    ushort4 h;
    h.x = f2bf(v.x); h.y = f2bf(v.y); h.z = f2bf(v.z); h.w = f2bf(v.w);
    ((ushort4*)dp)[k] = h;
}

__global__ void scan_partial(const int* __restrict__ cnt, int* __restrict__ bsum,
                             int N, int C) {
    __shared__ int red[SCAN_T];
    int b = blockIdx.x, t = threadIdx.x;
    int lo = b * C;
    int hi = lo + C; if (hi > N) hi = N;
    int s = 0;
    for (int i = lo + t; i < hi; i += SCAN_T) s += cnt[i];
    red[t] = s; __syncthreads();
    for (int o = SCAN_T / 2; o > 0; o >>= 1) {
        if (t < o) red[t] += red[t + o];
        __syncthreads();
    }
    if (t == 0) bsum[b] = red[0];
}

__global__ void scan_bsum(const int* __restrict__ bsum, int* __restrict__ bbase,
                          int* __restrict__ offN) {
    __shared__ int a[NB_SCAN], b[NB_SCAN];
    int t = threadIdx.x;
    a[t] = bsum[t]; __syncthreads();
    int* s = a; int* d = b;
    for (int o = 1; o < NB_SCAN; o <<= 1) {
        d[t] = s[t] + (t >= o ? s[t - o] : 0);
        __syncthreads();
        int* tmp = s; s = d; d = tmp;
    }
    bbase[t] = (t == 0) ? 0 : s[t - 1];
    if (t == NB_SCAN - 1) *offN = s[t];
}

__global__ void scan_write(const int* __restrict__ cnt, const int* __restrict__ bbase,
                           int* __restrict__ off, int N, int C) {
    __shared__ int buf[2][512];                 // C <= 512
    int b = blockIdx.x, t = threadIdx.x;
    int lo = b * C;
    for (int i = t; i < 512; i += SCAN_T)
        buf[0][i] = (i < C && lo + i < N) ? cnt[lo + i] : 0;
    __syncthreads();
    int cur = 0;
    for (int o = 1; o < 512; o <<= 1) {
        for (int i = t; i < 512; i += SCAN_T)
            buf[cur ^ 1][i] = buf[cur][i] + (i >= o ? buf[cur][i - o] : 0);
        cur ^= 1;
        __syncthreads();
    }
    int base = bbase[b];
    for (int i = t; i < 512; i += SCAN_T) {
        int idx = lo + i;
        if (i < C && idx < N)
            off[idx] = base + (i == 0 ? 0 : buf[cur][i - 1]);
    }
}

// Binned sort pass 1: group this block's edge chunk by coarse bucket and
// write packed (src<<8 | dst&255) into the bucket's contiguous region.
__launch_bounds__(256)
__global__ void binpass(const int* __restrict__ src, const int* __restrict__ dst,
                        const int* __restrict__ off, int* __restrict__ bfill,
                        unsigned int* __restrict__ binned, int E, int nbuck) {
    __shared__ int hcnt[MAXBUCK];
    __shared__ int hbase[MAXBUCK];
    int t = threadIdx.x;
    int nb = gridDim.x;
    int chunk = (E + nb - 1) / nb;
    int lo = blockIdx.x * chunk;
    int hi = lo + chunk; if (hi > E) hi = E;

    for (int i = t; i < nbuck; i += 256) hcnt[i] = 0;
    __syncthreads();
    for (int i = lo + t; i < hi; i += 256)
        atomicAdd(&hcnt[((unsigned)dst[i]) >> BSHIFT], 1);
    __syncthreads();
    for (int i = t; i < nbuck; i += 256) {
        int c = hcnt[i];
        hbase[i] = c > 0 ? (off[i << BSHIFT] + atomicAdd(&bfill[i], c)) : 0;
        hcnt[i] = 0;
    }
    __syncthreads();
    for (int i = lo + t; i < hi; i += 256) {
        int d = dst[i];
        int bu = ((unsigned)d) >> BSHIFT;
        int p = hbase[bu] + atomicAdd(&hcnt[bu], 1);
        binned[p] = (((unsigned)src[i]) << BSHIFT) | ((unsigned)d & 255u);
    }
}

// Binned sort pass 2: one block per bucket; place each edge at its node's
// CSR slot. Reads coalesced; writes land in the bucket's ~16KB region.
__launch_bounds__(256)
__global__ void sortpass(const unsigned int* __restrict__ binned,
                         const int* __restrict__ off,
                         int* __restrict__ sorted_src, int N) {
    __shared__ int soff[257];
    __shared__ int sfill[256];
    int b = blockIdx.x;
    int t = threadIdx.x;
    int n0 = b << BSHIFT;
    int nn = N - n0; if (nn > 256) nn = 256;
    for (int i = t; i <= nn; i += 256) soff[i] = off[n0 + i];
    sfill[t] = 0;
    __syncthreads();
    int lo = soff[0], hi = soff[nn];
    for (int i = lo + t; i < hi; i += 256) {
        unsigned int v = binned[i];
        int dlo = (int)(v & 255u);
        int p = soff[dlo] + atomicAdd(&sfill[dlo], 1);
        sorted_src[p] = (int)(v >> BSHIFT);
    }
}

// One wave per node. Lanes 0-31 handle even edges, 32-63 odd edges: each
// load instruction gathers TWO 128B bf16 rows (ushort2/lane). 8-deep unroll
// = 16 rows in flight. Writes f32 mean row into mean_out (= d_out scratch).
__launch_bounds__(256)
__global__ void agg_kernel(const unsigned short* __restrict__ xh,
                           const int* __restrict__ sorted_src,
                           const int* __restrict__ off,
                           float* __restrict__ mean_out, int N) {
    int wave = threadIdx.x >> 6;
    int lane = threadIdx.x & 63;
    int node = blockIdx.x * 4 + wave;
    if (node >= N) return;

    int s0 = off[node];
    int s1 = off[node + 1];
    int deg = s1 - s0;
    int half = lane >> 5;          // which edge of the pair
    int l2 = lane & 31;            // channel pair index

    float2 acc[8];
    #pragma unroll
    for (int u = 0; u < 8; ++u) { acc[u].x = 0.f; acc[u].y = 0.f; }

    for (int base = s0; base < s1; base += 64) {
        int cc = s1 - base; if (cc > 64) cc = 64;
        int myidx = (lane < cc) ? sorted_src[base + lane] : 0;
        int pairs = cc >> 1;
        int s = 0;
        for (; s + 8 <= pairs; s += 8) {
            unsigned int vv[8];
            #pragma unroll
            for (int u = 0; u < 8; ++u) {
                int id = __shfl(myidx, 2 * (s + u) + half);
                vv[u] = *(const unsigned int*)(xh + (size_t)id * DFEAT + l2 * 2);
            }
            #pragma unroll
            for (int u = 0; u < 8; ++u) {
                acc[u].x += bf2f_lo(vv[u]);
                acc[u].y += bf2f_hi(vv[u]);
            }
        }
        for (; s < pairs; ++s) {
            int id = __shfl(myidx, 2 * s + half);
            unsigned int v = *(const unsigned int*)(xh + (size_t)id * DFEAT + l2 * 2);
            acc[0].x += bf2f_lo(v);
            acc[0].y += bf2f_hi(v);
        }
        if (cc & 1) {
            int id = __shfl(myidx, cc - 1);
            unsigned int v = *(const unsigned int*)(xh + (size_t)id * DFEAT + l2 * 2);
            if (half == 0) {               // only even half adds the odd edge
                acc[1].x += bf2f_lo(v);
                acc[1].y += bf2f_hi(v);
            }
        }
    }

    float2 t;
    t.x = ((acc[0].x + acc[1].x) + (acc[2].x + acc[3].x))
        + ((acc[4].x + acc[5].x) + (acc[6].x + acc[7].x));
    t.y = ((acc[0].y + acc[1].y) + (acc[2].y + acc[3].y))
        + ((acc[4].y + acc[5].y) + (acc[6].y + acc[7].y));
    t.x += __shfl_xor(t.x, 32);
    t.y += __shfl_xor(t.y, 32);

    float inv = 1.0f / fmaxf((float)deg, 1.0f);
    if (lane < 32) {
        float2 m; m.x = t.x * inv; m.y = t.y * inv;
        ((float2*)mean_out)[(size_t)node * 32 + l2] = m;
    }
}

// out = [mean | x]_bf16 @ [Wl ; Wr]_bf16 + b, 16-node tiles per wave.
__launch_bounds__(256)
__global__ void gemm_kernel(const float* __restrict__ meanf,    // == out (scratch)
                            const unsigned short* __restrict__ xh,
                            const unsigned short* __restrict__ wl16,
                            const unsigned short* __restrict__ wr16,
                            const float* __restrict__ bl,
                            float* __restrict__ out, int N, int ntiles) {
    int lane = threadIdx.x & 63;
    int n15 = lane & 15;
    int quad = lane >> 4;
    int wid = (blockIdx.x * blockDim.x + threadIdx.x) >> 6;
    int nwaves = (gridDim.x * blockDim.x) >> 6;

    bf16x8 bfrag[4][4];
    #pragma unroll
    for (int kk = 0; kk < 4; ++kk) {
        const unsigned short* W = (kk < 2) ? wl16 : wr16;
        int kbase = (kk & 1) * 32 + quad * 8;
        #pragma unroll
        for (int nt = 0; nt < 4; ++nt) {
            #pragma unroll
            for (int j = 0; j < 8; ++j)
                bfrag[kk][nt][j] = (short)W[(kbase + j) * DFEAT + nt * 16 + n15];
        }
    }
    float bias[4];
    #pragma unroll
    for (int nt = 0; nt < 4; ++nt) bias[nt] = bl[nt * 16 + n15];

    for (int t = wid; t < ntiles; t += nwaves) {
        int n0 = t * 16;
        int row = n0 + n15; if (row >= N) row = N - 1;

        bf16x8 afrag[4];
        #pragma unroll
        for (int kk = 0; kk < 2; ++kk) {
            const float* p = meanf + (size_t)row * DFEAT + kk * 32 + quad * 8;
            float4 lo = *(const float4*)p;
            float4 hi = *(const float4*)(p + 4);
            afrag[kk][0] = (short)f2bf(lo.x); afrag[kk][1] = (short)f2bf(lo.y);
            afrag[kk][2] = (short)f2bf(lo.z); afrag[kk][3] = (short)f2bf(lo.w);
            afrag[kk][4] = (short)f2bf(hi.x); afrag[kk][5] = (short)f2bf(hi.y);
            afrag[kk][6] = (short)f2bf(hi.z); afrag[kk][7] = (short)f2bf(hi.w);
        }
        #pragma unroll
        for (int kk = 0; kk < 2; ++kk)
            afrag[2 + kk] = *(const bf16x8*)(xh + (size_t)row * DFEAT + kk * 32 + quad * 8);

        #pragma unroll
        for (int nt = 0; nt < 4; ++nt) {
            f32x4 c = {0.f, 0.f, 0.f, 0.f};
            #pragma unroll
            for (int kk = 0; kk < 4; ++kk)
                c = __builtin_amdgcn_mfma_f32_16x16x32_bf16(afrag[kk], bfrag[kk][nt], c, 0, 0, 0);
            #pragma unroll
            for (int r = 0; r < 4; ++r) {
                int orow = n0 + quad * 4 + r;
                if (orow < N)
                    out[(size_t)orow * DFEAT + nt * 16 + n15] = c[r] + bias[nt];
            }
        }
    }
}

extern "C" void kernel_launch(void* const* d_in, const int* in_sizes, int n_in,
                              void* d_out, int out_size, void* d_ws, size_t ws_size,
                              hipStream_t stream) {
    const float* x  = (const float*)d_in[0];
    const int*   ei = (const int*)d_in[1];     // [2,E] flat: src then dst
    const float* Wl = (const float*)d_in[2];
    const float* bl = (const float*)d_in[3];
    const float* Wr = (const float*)d_in[4];
    float* out = (float*)d_out;

    const int N = in_sizes[0] / DFEAT;         // 100000
    const int E = in_sizes[1] / 2;             // 1600000
    const int* src = ei;
    const int* dst = ei + E;

    const int C = (N + NB_SCAN - 1) / NB_SCAN; // 391 (<= 512)
    const int nbuck = (N + 255) >> BSHIFT;     // 391 (<= MAXBUCK)

    // Workspace: [cnt N][bfill 512][off N+16][bsum 256][bbase 256][sorted_src E][wl16][wr16][xh]
    int* ws = (int*)d_ws;
    int* cnt        = ws;
    int* bfill      = cnt + N;
    int* off        = bfill + MAXBUCK;
    int* bsum       = off + N + 16;
    int* bbase      = bsum + NB_SCAN;
    int* sorted_src = bbase + NB_SCAN;
    unsigned short* wl16 = (unsigned short*)(sorted_src + E);
    unsigned short* wr16 = wl16 + DFEAT * DFEAT;
    unsigned short* xh   = wr16 + DFEAT * DFEAT;

    unsigned int* binned = (unsigned int*)d_out;   // staging, consumed before agg

    hipMemsetAsync(cnt, 0, ((size_t)N + MAXBUCK) * sizeof(int), stream);

    int nx4 = N * DFEAT / 4;
    convert_kernel<<<(2048 + nx4 + 255) / 256, 256, 0, stream>>>(
        x, Wl, Wr, xh, wl16, wr16, nx4);

    hist_kernel<<<(E / 4 + 255) / 256, 256, 0, stream>>>(dst, cnt, E);
    scan_partial<<<NB_SCAN, SCAN_T, 0, stream>>>(cnt, bsum, N, C);
    scan_bsum<<<1, NB_SCAN, 0, stream>>>(bsum, bbase, off + N);
    scan_write<<<NB_SCAN, SCAN_T, 0, stream>>>(cnt, bbase, off, N, C);

    binpass<<<256, 256, 0, stream>>>(src, dst, off, bfill, binned, E, nbuck);
    sortpass<<<nbuck, 256, 0, stream>>>(binned, off, sorted_src, N);

    agg_kernel<<<(N + 3) / 4, 256, 0, stream>>>(xh, sorted_src, off, out, N);

    int ntiles = (N + 15) / 16;                // 6250
    gemm_kernel<<<400, 256, 0, stream>>>(out, xh, wl16, wr16, bl, out, N, ntiles);
}

// Round 6
// 202.277 us; speedup vs baseline: 3.8179x; 1.3191x over previous
//
#include <hip/hip_runtime.h>

// GraphSAGEConv: out_i = mean_{j in N(i)} x_j @ W_l + b_l + x_i @ W_r
// N=100000, E=1600000, D_in=D_out=64.
//
// Pipeline (no N-wide global histogram — global atomics cost ~32B of
// memory-side traffic each, measured 50MB WRITE_SIZE in R5's hist):
//   convert:  x -> bf16 table xh, Wl/Wr -> bf16
//   bhist:    per-block LDS histogram of 391 coarse buckets (256 nodes each),
//             one global atomic per (block,bucket).
//   bscan:    one-block scan -> bbase[] bucket bases.
//   binpass:  per-block LDS bucket grouping, space reserved per (block,bucket),
//             edges packed (src<<8)|(dst&255) written line-dense into the
//             bucket's region of a staging array in d_out.
//   sortpass: one block per bucket: fine 256-counter LDS histogram + scan
//             (writes off[] itself, coalesced), then places sorted_src.
//   agg_kernel: one wave per node, 2 edges per load instr (half-wave x
//             ushort2), 16 bf16 rows in flight; f32 mean rows -> d_out.
//   gemm_kernel: out = [mean|x]_bf16 @ [Wl;Wr]_bf16 + b via
//             mfma_f32_16x16x32_bf16, 16-node tiles, in-place over d_out.

#define DFEAT 64
#define BSHIFT 8                     // 256 nodes per coarse bucket
#define MAXBUCK 512                  // supports N <= 131072

typedef short bf16x8 __attribute__((ext_vector_type(8)));
typedef float f32x4 __attribute__((ext_vector_type(4)));

static __device__ __forceinline__ unsigned short f2bf(float f) {
    unsigned int u = __float_as_uint(f);
    unsigned int r = (u + 0x7FFFu + ((u >> 16) & 1u)) >> 16;   // RNE
    return (unsigned short)r;
}
static __device__ __forceinline__ float bf2f_lo(unsigned int u) {
    return __uint_as_float(u << 16);
}
static __device__ __forceinline__ float bf2f_hi(unsigned int u) {
    return __uint_as_float(u & 0xFFFF0000u);
}

__global__ void convert_kernel(const float* __restrict__ x,
                               const float* __restrict__ Wl,
                               const float* __restrict__ Wr,
                               unsigned short* __restrict__ xh,
                               unsigned short* __restrict__ wl16,
                               unsigned short* __restrict__ wr16,
                               int nx4) {
    int i = blockIdx.x * blockDim.x + threadIdx.x;
    const float* sp; unsigned short* dp; int k;
    if (i < 1024)      { sp = Wl; dp = wl16; k = i; }
    else if (i < 2048) { sp = Wr; dp = wr16; k = i - 1024; }
    else if (i - 2048 < nx4) { sp = x; dp = xh; k = i - 2048; }
    else return;
    float4 v = ((const float4*)sp)[k];
    ushort4 h;
    h.x = f2bf(v.x); h.y = f2bf(v.y); h.z = f2bf(v.z); h.w = f2bf(v.w);
    ((ushort4*)dp)[k] = h;
}

// Coarse-bucket histogram: LDS-local, one global atomic per (block,bucket).
__launch_bounds__(256)
__global__ void bhist(const int* __restrict__ dst, int* __restrict__ bcnt,
                      int E, int nbuck) {
    __shared__ int h[MAXBUCK];
    int t = threadIdx.x;
    for (int i = t; i < nbuck; i += 256) h[i] = 0;
    __syncthreads();
    int nb = gridDim.x;
    int chunk = (E + nb - 1) / nb;
    int lo = blockIdx.x * chunk;
    int hi = lo + chunk; if (hi > E) hi = E;
    for (int i = lo + t; i < hi; i += 256)
        atomicAdd(&h[((unsigned)dst[i]) >> BSHIFT], 1);
    __syncthreads();
    for (int i = t; i < nbuck; i += 256)
        if (h[i]) atomicAdd(&bcnt[i], h[i]);
}

// One-block exclusive scan of bucket counts -> bbase[0..nbuck].
__global__ void bscan(const int* __restrict__ bcnt, int* __restrict__ bbase,
                      int nbuck) {
    __shared__ int a[2][MAXBUCK];
    int t = threadIdx.x;                       // blockDim = MAXBUCK
    a[0][t] = (t < nbuck) ? bcnt[t] : 0;
    __syncthreads();
    int cur = 0;
    for (int o = 1; o < MAXBUCK; o <<= 1) {
        a[cur ^ 1][t] = a[cur][t] + ((t >= o) ? a[cur][t - o] : 0);
        cur ^= 1;
        __syncthreads();
    }
    if (t < nbuck) bbase[t] = (t == 0) ? 0 : a[cur][t - 1];
    if (t == 0) bbase[nbuck] = a[cur][nbuck - 1];
}

// Binned sort pass 1: group this block's edge chunk by coarse bucket and
// write packed (src<<8 | dst&255) into the bucket's contiguous region.
__launch_bounds__(256)
__global__ void binpass(const int* __restrict__ src, const int* __restrict__ dst,
                        const int* __restrict__ bbase, int* __restrict__ bfill,
                        unsigned int* __restrict__ binned, int E, int nbuck) {
    __shared__ int hcnt[MAXBUCK];
    __shared__ int hbase[MAXBUCK];
    int t = threadIdx.x;
    int nb = gridDim.x;
    int chunk = (E + nb - 1) / nb;
    int lo = blockIdx.x * chunk;
    int hi = lo + chunk; if (hi > E) hi = E;

    for (int i = t; i < nbuck; i += 256) hcnt[i] = 0;
    __syncthreads();
    for (int i = lo + t; i < hi; i += 256)
        atomicAdd(&hcnt[((unsigned)dst[i]) >> BSHIFT], 1);
    __syncthreads();
    for (int i = t; i < nbuck; i += 256) {
        int c = hcnt[i];
        hbase[i] = c > 0 ? (bbase[i] + atomicAdd(&bfill[i], c)) : 0;
        hcnt[i] = 0;
    }
    __syncthreads();
    for (int i = lo + t; i < hi; i += 256) {
        int d = dst[i];
        int bu = ((unsigned)d) >> BSHIFT;
        int p = hbase[bu] + atomicAdd(&hcnt[bu], 1);
        binned[p] = (((unsigned)src[i]) << BSHIFT) | ((unsigned)d & 255u);
    }
}

// Binned sort pass 2: one block per bucket. Fine LDS histogram + scan gives
// off[] (written coalesced here) and the placement bases for sorted_src.
__launch_bounds__(256)
__global__ void sortpass(const unsigned int* __restrict__ binned,
                         const int* __restrict__ bbase,
                         int* __restrict__ off, int* __restrict__ sorted_src,
                         int N, int nbuck) {
    __shared__ int scnt[256];
    __shared__ int sx[2][256];
    __shared__ int sfill[256];
    int b = blockIdx.x, t = threadIdx.x;
    int n0 = b << BSHIFT;
    int nn = N - n0; if (nn > 256) nn = 256;
    scnt[t] = 0; sfill[t] = 0;
    __syncthreads();
    int lo = bbase[b], hi = bbase[b + 1];
    for (int i = lo + t; i < hi; i += 256)
        atomicAdd(&scnt[binned[i] & 255u], 1);
    __syncthreads();
    sx[0][t] = scnt[t];
    __syncthreads();
    int cur = 0;
    for (int o = 1; o < 256; o <<= 1) {
        sx[cur ^ 1][t] = sx[cur][t] + ((t >= o) ? sx[cur][t - o] : 0);
        cur ^= 1;
        __syncthreads();
    }
    int myoff = lo + ((t == 0) ? 0 : sx[cur][t - 1]);
    if (t < nn) off[n0 + t] = myoff;
    if (b == nbuck - 1 && t == 0) off[N] = bbase[nbuck];
    scnt[t] = myoff;                 // reuse as placement base
    __syncthreads();
    for (int i = lo + t; i < hi; i += 256) {
        unsigned int v = binned[i];
        int d = (int)(v & 255u);
        int p = scnt[d] + atomicAdd(&sfill[d], 1);
        sorted_src[p] = (int)(v >> BSHIFT);
    }
}

// One wave per node. Lanes 0-31 handle even edges, 32-63 odd edges: each
// load instruction gathers TWO 128B bf16 rows (ushort2/lane). 8-deep unroll
// = 16 rows in flight. Writes f32 mean row into mean_out (= d_out scratch).
__launch_bounds__(256)
__global__ void agg_kernel(const unsigned short* __restrict__ xh,
                           const int* __restrict__ sorted_src,
                           const int* __restrict__ off,
                           float* __restrict__ mean_out, int N) {
    int wave = threadIdx.x >> 6;
    int lane = threadIdx.x & 63;
    int node = blockIdx.x * 4 + wave;
    if (node >= N) return;

    int s0 = off[node];
    int s1 = off[node + 1];
    int deg = s1 - s0;
    int half = lane >> 5;          // which edge of the pair
    int l2 = lane & 31;            // channel pair index

    float2 acc[8];
    #pragma unroll
    for (int u = 0; u < 8; ++u) { acc[u].x = 0.f; acc[u].y = 0.f; }

    for (int base = s0; base < s1; base += 64) {
        int cc = s1 - base; if (cc > 64) cc = 64;
        int myidx = (lane < cc) ? sorted_src[base + lane] : 0;
        int pairs = cc >> 1;
        int s = 0;
        for (; s + 8 <= pairs; s += 8) {
            unsigned int vv[8];
            #pragma unroll
            for (int u = 0; u < 8; ++u) {
                int id = __shfl(myidx, 2 * (s + u) + half);
                vv[u] = *(const unsigned int*)(xh + (size_t)id * DFEAT + l2 * 2);
            }
            #pragma unroll
            for (int u = 0; u < 8; ++u) {
                acc[u].x += bf2f_lo(vv[u]);
                acc[u].y += bf2f_hi(vv[u]);
            }
        }
        for (; s < pairs; ++s) {
            int id = __shfl(myidx, 2 * s + half);
            unsigned int v = *(const unsigned int*)(xh + (size_t)id * DFEAT + l2 * 2);
            acc[0].x += bf2f_lo(v);
            acc[0].y += bf2f_hi(v);
        }
        if (cc & 1) {
            int id = __shfl(myidx, cc - 1);
            unsigned int v = *(const unsigned int*)(xh + (size_t)id * DFEAT + l2 * 2);
            if (half == 0) {               // only even half adds the odd edge
                acc[1].x += bf2f_lo(v);
                acc[1].y += bf2f_hi(v);
            }
        }
    }

    float2 t;
    t.x = ((acc[0].x + acc[1].x) + (acc[2].x + acc[3].x))
        + ((acc[4].x + acc[5].x) + (acc[6].x + acc[7].x));
    t.y = ((acc[0].y + acc[1].y) + (acc[2].y + acc[3].y))
        + ((acc[4].y + acc[5].y) + (acc[6].y + acc[7].y));
    t.x += __shfl_xor(t.x, 32);
    t.y += __shfl_xor(t.y, 32);

    float inv = 1.0f / fmaxf((float)deg, 1.0f);
    if (lane < 32) {
        float2 m; m.x = t.x * inv; m.y = t.y * inv;
        ((float2*)mean_out)[(size_t)node * 32 + l2] = m;
    }
}

// out = [mean | x]_bf16 @ [Wl ; Wr]_bf16 + b, 16-node tiles per wave.
__launch_bounds__(256)
__global__ void gemm_kernel(const float* __restrict__ meanf,    // == out (scratch)
                            const unsigned short* __restrict__ xh,
                            const unsigned short* __restrict__ wl16,
                            const unsigned short* __restrict__ wr16,
                            const float* __restrict__ bl,
                            float* __restrict__ out, int N, int ntiles) {
    int lane = threadIdx.x & 63;
    int n15 = lane & 15;
    int quad = lane >> 4;
    int wid = (blockIdx.x * blockDim.x + threadIdx.x) >> 6;
    int nwaves = (gridDim.x * blockDim.x) >> 6;

    bf16x8 bfrag[4][4];
    #pragma unroll
    for (int kk = 0; kk < 4; ++kk) {
        const unsigned short* W = (kk < 2) ? wl16 : wr16;
        int kbase = (kk & 1) * 32 + quad * 8;
        #pragma unroll
        for (int nt = 0; nt < 4; ++nt) {
            #pragma unroll
            for (int j = 0; j < 8; ++j)
                bfrag[kk][nt][j] = (short)W[(kbase + j) * DFEAT + nt * 16 + n15];
        }
    }
    float bias[4];
    #pragma unroll
    for (int nt = 0; nt < 4; ++nt) bias[nt] = bl[nt * 16 + n15];

    for (int t = wid; t < ntiles; t += nwaves) {
        int n0 = t * 16;
        int row = n0 + n15; if (row >= N) row = N - 1;

        bf16x8 afrag[4];
        #pragma unroll
        for (int kk = 0; kk < 2; ++kk) {
            const float* p = meanf + (size_t)row * DFEAT + kk * 32 + quad * 8;
            float4 lo = *(const float4*)p;
            float4 hi = *(const float4*)(p + 4);
            afrag[kk][0] = (short)f2bf(lo.x); afrag[kk][1] = (short)f2bf(lo.y);
            afrag[kk][2] = (short)f2bf(lo.z); afrag[kk][3] = (short)f2bf(lo.w);
            afrag[kk][4] = (short)f2bf(hi.x); afrag[kk][5] = (short)f2bf(hi.y);
            afrag[kk][6] = (short)f2bf(hi.z); afrag[kk][7] = (short)f2bf(hi.w);
        }
        #pragma unroll
        for (int kk = 0; kk < 2; ++kk)
            afrag[2 + kk] = *(const bf16x8*)(xh + (size_t)row * DFEAT + kk * 32 + quad * 8);

        #pragma unroll
        for (int nt = 0; nt < 4; ++nt) {
            f32x4 c = {0.f, 0.f, 0.f, 0.f};
            #pragma unroll
            for (int kk = 0; kk < 4; ++kk)
                c = __builtin_amdgcn_mfma_f32_16x16x32_bf16(afrag[kk], bfrag[kk][nt], c, 0, 0, 0);
            #pragma unroll
            for (int r = 0; r < 4; ++r) {
                int orow = n0 + quad * 4 + r;
                if (orow < N)
                    out[(size_t)orow * DFEAT + nt * 16 + n15] = c[r] + bias[nt];
            }
        }
    }
}

extern "C" void kernel_launch(void* const* d_in, const int* in_sizes, int n_in,
                              void* d_out, int out_size, void* d_ws, size_t ws_size,
                              hipStream_t stream) {
    const float* x  = (const float*)d_in[0];
    const int*   ei = (const int*)d_in[1];     // [2,E] flat: src then dst
    const float* Wl = (const float*)d_in[2];
    const float* bl = (const float*)d_in[3];
    const float* Wr = (const float*)d_in[4];
    float* out = (float*)d_out;

    const int N = in_sizes[0] / DFEAT;         // 100000
    const int E = in_sizes[1] / 2;             // 1600000
    const int* src = ei;
    const int* dst = ei + E;

    const int nbuck = (N + 255) >> BSHIFT;     // 391 (<= MAXBUCK)

    // Workspace: [bcnt 512][bfill 512][bbase 528][off N+16][sorted_src E][wl16][wr16][xh]
    int* ws = (int*)d_ws;
    int* bcnt       = ws;
    int* bfill      = bcnt + MAXBUCK;
    int* bbase      = bfill + MAXBUCK;
    int* off        = bbase + MAXBUCK + 16;
    int* sorted_src = off + N + 16;
    unsigned short* wl16 = (unsigned short*)(sorted_src + E);
    unsigned short* wr16 = wl16 + DFEAT * DFEAT;
    unsigned short* xh   = wr16 + DFEAT * DFEAT;

    unsigned int* binned = (unsigned int*)d_out;   // staging, consumed before agg

    hipMemsetAsync(bcnt, 0, 2 * MAXBUCK * sizeof(int), stream);

    int nx4 = N * DFEAT / 4;
    convert_kernel<<<(2048 + nx4 + 255) / 256, 256, 0, stream>>>(
        x, Wl, Wr, xh, wl16, wr16, nx4);

    bhist<<<256, 256, 0, stream>>>(dst, bcnt, E, nbuck);
    bscan<<<1, MAXBUCK, 0, stream>>>(bcnt, bbase, nbuck);
    binpass<<<256, 256, 0, stream>>>(src, dst, bbase, bfill, binned, E, nbuck);
    sortpass<<<nbuck, 256, 0, stream>>>(binned, bbase, off, sorted_src, N, nbuck);

    agg_kernel<<<(N + 3) / 4, 256, 0, stream>>>(xh, sorted_src, off, out, N);

    int ntiles = (N + 15) / 16;                // 6250
    gemm_kernel<<<400, 256, 0, stream>>>(out, xh, wl16, wr16, bl, out, N, ntiles);
}

// Round 7
// 196.786 us; speedup vs baseline: 3.9245x; 1.0279x over previous
//
#include <hip/hip_runtime.h>

// GraphSAGEConv: out_i = mean_{j in N(i)} x_j @ W_l + b_l + x_i @ W_r
// N=100000, E=1600000, D_in=D_out=64.
//
// 5 dispatches:
//   memset:  bcnt/bfill (tiny)
//   prep:    convert x->bf16 xh, Wl/Wr->bf16  +  coarse bucket histogram
//            (256-node buckets, per-block LDS hist, 1 global atomic/(blk,bkt))
//   bscan:   1-block scan -> bbase[]
//   binpass: group edges by coarse bucket, packed (src<<8)|(dst&255), written
//            line-dense into bucket regions of binned (in d_ws)
//   sage_fused: one block per 64 nodes (quarter bucket):
//            - filter+fine-sort its edges into LDS (no global sorted_src/off)
//            - per-wave aggregation: 16 nodes/wave, indices from LDS, half-wave
//              ushort2 gathers of 128B bf16 rows, 8-deep ILP, f32 accumulate
//            - means staged bf16 in LDS (72-short row pitch: conflict-free)
//            - each wave computes its 16-col quadrant of the 64x64 out tile
//              via 16x mfma_f32_16x16x32_bf16 (fuses both GEMMs, K=128)

#define DFEAT 64
#define MAXBUCK 512                  // coarse buckets (256 nodes), N <= 131072
#define SORT_CAP 2048                // LDS edge capacity per 64-node block
#define MLD 72                       // means row pitch in shorts (bank-safe)

typedef short bf16x8 __attribute__((ext_vector_type(8)));
typedef float f32x4 __attribute__((ext_vector_type(4)));

static __device__ __forceinline__ unsigned short f2bf(float f) {
    unsigned int u = __float_as_uint(f);
    unsigned int r = (u + 0x7FFFu + ((u >> 16) & 1u)) >> 16;   // RNE
    return (unsigned short)r;
}
static __device__ __forceinline__ float bf2f_lo(unsigned int u) {
    return __uint_as_float(u << 16);
}
static __device__ __forceinline__ float bf2f_hi(unsigned int u) {
    return __uint_as_float(u & 0xFFFF0000u);
}

// convert (blocks [0, convBlocks)) + coarse histogram (blocks [convBlocks, +HB))
__launch_bounds__(256)
__global__ void prep(const float* __restrict__ x,
                     const float* __restrict__ Wl,
                     const float* __restrict__ Wr,
                     const int* __restrict__ dst,
                     unsigned short* __restrict__ xh,
                     unsigned short* __restrict__ wl16,
                     unsigned short* __restrict__ wr16,
                     int* __restrict__ bcnt,
                     int nx4, int convBlocks, int E, int nbuck) {
    __shared__ int h[MAXBUCK];
    int b = blockIdx.x, t = threadIdx.x;
    if (b < convBlocks) {
        int i = b * 256 + t;
        const float* sp; unsigned short* dp; int k;
        if (i < 1024)      { sp = Wl; dp = wl16; k = i; }
        else if (i < 2048) { sp = Wr; dp = wr16; k = i - 1024; }
        else if (i - 2048 < nx4) { sp = x; dp = xh; k = i - 2048; }
        else return;
        float4 v = ((const float4*)sp)[k];
        ushort4 hh;
        hh.x = f2bf(v.x); hh.y = f2bf(v.y); hh.z = f2bf(v.z); hh.w = f2bf(v.w);
        ((ushort4*)dp)[k] = hh;
        return;
    }
    int hb = b - convBlocks;                    // 0..255
    for (int i = t; i < nbuck; i += 256) h[i] = 0;
    __syncthreads();
    int chunk = (E + 255) / 256;
    int lo = hb * chunk;
    int hi = lo + chunk; if (hi > E) hi = E;
    for (int i = lo + t; i < hi; i += 256)
        atomicAdd(&h[((unsigned)dst[i]) >> 8], 1);
    __syncthreads();
    for (int i = t; i < nbuck; i += 256)
        if (h[i]) atomicAdd(&bcnt[i], h[i]);
}

// One-block exclusive scan of bucket counts -> bbase[0..nbuck].
__global__ void bscan(const int* __restrict__ bcnt, int* __restrict__ bbase,
                      int nbuck) {
    __shared__ int a[2][MAXBUCK];
    int t = threadIdx.x;                        // blockDim = MAXBUCK
    a[0][t] = (t < nbuck) ? bcnt[t] : 0;
    __syncthreads();
    int cur = 0;
    for (int o = 1; o < MAXBUCK; o <<= 1) {
        a[cur ^ 1][t] = a[cur][t] + ((t >= o) ? a[cur][t - o] : 0);
        cur ^= 1;
        __syncthreads();
    }
    if (t < nbuck) bbase[t] = (t == 0) ? 0 : a[cur][t - 1];
    if (t == 0) bbase[nbuck] = a[cur][nbuck - 1];
}

// Group edges by coarse bucket; write packed (src<<8 | dst&255) line-dense.
__launch_bounds__(256)
__global__ void binpass(const int* __restrict__ src, const int* __restrict__ dst,
                        const int* __restrict__ bbase, int* __restrict__ bfill,
                        unsigned int* __restrict__ binned, int E, int nbuck) {
    __shared__ int hcnt[MAXBUCK];
    __shared__ int hbase[MAXBUCK];
    int t = threadIdx.x;
    int chunk = (E + 255) / 256;
    int lo = blockIdx.x * chunk;
    int hi = lo + chunk; if (hi > E) hi = E;

    for (int i = t; i < nbuck; i += 256) hcnt[i] = 0;
    __syncthreads();
    for (int i = lo + t; i < hi; i += 256)
        atomicAdd(&hcnt[((unsigned)dst[i]) >> 8], 1);
    __syncthreads();
    for (int i = t; i < nbuck; i += 256) {
        int c = hcnt[i];
        hbase[i] = c > 0 ? (bbase[i] + atomicAdd(&bfill[i], c)) : 0;
        hcnt[i] = 0;
    }
    __syncthreads();
    for (int i = lo + t; i < hi; i += 256) {
        int d = dst[i];
        int bu = ((unsigned)d) >> 8;
        int p = hbase[bu] + atomicAdd(&hcnt[bu], 1);
        binned[p] = (((unsigned)src[i]) << 8) | ((unsigned)d & 255u);
    }
}

// Fused fine-sort + aggregate + dual-GEMM. One block per 64 nodes.
__launch_bounds__(256)
__global__ void sage_fused(const unsigned short* __restrict__ xh,
                           const unsigned int* __restrict__ binned,
                           const int* __restrict__ bbase,
                           const unsigned short* __restrict__ wl16,
                           const unsigned short* __restrict__ wr16,
                           const float* __restrict__ bl,
                           float* __restrict__ out, int N) {
    __shared__ int scnt[64];
    __shared__ int sbase[64];
    __shared__ int sfill[64];
    __shared__ int sortbuf[SORT_CAP];
    __shared__ unsigned short means[64 * MLD];   // 9216 B

    int cb = blockIdx.x >> 2;       // coarse bucket
    int q  = blockIdx.x & 3;        // 64-node quarter
    int n0 = (cb << 8) + (q << 6);
    if (n0 >= N) return;
    int nn = N - n0; if (nn > 64) nn = 64;

    int t = threadIdx.x;
    int w = t >> 6;
    int lane = t & 63;

    // ---- fine histogram (filtered to our quarter) ----
    if (t < 64) { scnt[t] = 0; sfill[t] = 0; }
    __syncthreads();
    int elo = bbase[cb], ehi = bbase[cb + 1];
    for (int i = elo + t; i < ehi; i += 256) {
        unsigned int v = binned[i];
        int dlo = (int)(v & 255u);
        if ((dlo >> 6) == q) atomicAdd(&scnt[dlo & 63], 1);
    }
    __syncthreads();
    // ---- exclusive scan of 64 counters (wave 0, shfl) ----
    if (w == 0) {
        int c = scnt[lane];
        int v = c;
        #pragma unroll
        for (int o = 1; o < 64; o <<= 1) {
            int u = __shfl_up(v, o);
            if (lane >= o) v += u;
        }
        sbase[lane] = v - c;
    }
    __syncthreads();
    // ---- place edges into LDS ----
    for (int i = elo + t; i < ehi; i += 256) {
        unsigned int v = binned[i];
        int dlo = (int)(v & 255u);
        if ((dlo >> 6) == q) {
            int d = dlo & 63;
            int p = sbase[d] + atomicAdd(&sfill[d], 1);
            if (p < SORT_CAP) sortbuf[p] = (int)(v >> 8);
        }
    }
    __syncthreads();

    // ---- aggregation: wave w handles nodes w*16 .. w*16+15 ----
    int half = lane >> 5;
    int l2 = lane & 31;
    for (int m = 0; m < 16; ++m) {
        int d = w * 16 + m;
        if (d >= nn) break;
        int s0 = sbase[d];
        int deg = scnt[d];
        int s1 = s0 + deg; if (s1 > SORT_CAP) s1 = SORT_CAP;

        float2 acc[8];
        #pragma unroll
        for (int u = 0; u < 8; ++u) { acc[u].x = 0.f; acc[u].y = 0.f; }

        for (int base = s0; base < s1; base += 64) {
            int cc = s1 - base; if (cc > 64) cc = 64;
            int myidx = (lane < cc) ? sortbuf[base + lane] : 0;
            int pairs = cc >> 1;
            int s = 0;
            for (; s + 8 <= pairs; s += 8) {
                unsigned int vv[8];
                #pragma unroll
                for (int u = 0; u < 8; ++u) {
                    int id = __shfl(myidx, 2 * (s + u) + half);
                    vv[u] = *(const unsigned int*)(xh + (size_t)id * DFEAT + l2 * 2);
                }
                #pragma unroll
                for (int u = 0; u < 8; ++u) {
                    acc[u].x += bf2f_lo(vv[u]);
                    acc[u].y += bf2f_hi(vv[u]);
                }
            }
            for (; s < pairs; ++s) {
                int id = __shfl(myidx, 2 * s + half);
                unsigned int v = *(const unsigned int*)(xh + (size_t)id * DFEAT + l2 * 2);
                acc[0].x += bf2f_lo(v);
                acc[0].y += bf2f_hi(v);
            }
            if (cc & 1) {
                int id = __shfl(myidx, cc - 1);
                unsigned int v = *(const unsigned int*)(xh + (size_t)id * DFEAT + l2 * 2);
                if (half == 0) {
                    acc[1].x += bf2f_lo(v);
                    acc[1].y += bf2f_hi(v);
                }
            }
        }

        float2 s2;
        s2.x = ((acc[0].x + acc[1].x) + (acc[2].x + acc[3].x))
             + ((acc[4].x + acc[5].x) + (acc[6].x + acc[7].x));
        s2.y = ((acc[0].y + acc[1].y) + (acc[2].y + acc[3].y))
             + ((acc[4].y + acc[5].y) + (acc[6].y + acc[7].y));
        s2.x += __shfl_xor(s2.x, 32);
        s2.y += __shfl_xor(s2.y, 32);

        if (lane < 32) {
            float inv = 1.0f / fmaxf((float)deg, 1.0f);
            unsigned int pk = (unsigned int)f2bf(s2.x * inv)
                            | ((unsigned int)f2bf(s2.y * inv) << 16);
            *(unsigned int*)&means[d * MLD + l2 * 2] = pk;
        }
    }
    __syncthreads();

    // ---- GEMM: wave w = column quadrant nt; 4 row-tiles x 4 k-chunks ----
    int nt = w;
    int n15 = lane & 15;
    int quad = lane >> 4;

    bf16x8 bfrag[4];
    #pragma unroll
    for (int kk = 0; kk < 4; ++kk) {
        const unsigned short* W = (kk < 2) ? wl16 : wr16;
        int kbase = (kk & 1) * 32 + quad * 8;
        #pragma unroll
        for (int j = 0; j < 8; ++j)
            bfrag[kk][j] = (short)W[(kbase + j) * DFEAT + nt * 16 + n15];
    }
    float bias = bl[nt * 16 + n15];

    #pragma unroll
    for (int tt = 0; tt < 4; ++tt) {
        int m = tt * 16 + n15;                       // local node row (A row)
        int grow = n0 + m; if (grow >= N) grow = N - 1;

        bf16x8 a0 = *(const bf16x8*)&means[m * MLD + quad * 8];
        bf16x8 a1 = *(const bf16x8*)&means[m * MLD + 32 + quad * 8];
        bf16x8 a2 = *(const bf16x8*)(xh + (size_t)grow * DFEAT + quad * 8);
        bf16x8 a3 = *(const bf16x8*)(xh + (size_t)grow * DFEAT + 32 + quad * 8);

        f32x4 c = {0.f, 0.f, 0.f, 0.f};
        c = __builtin_amdgcn_mfma_f32_16x16x32_bf16(a0, bfrag[0], c, 0, 0, 0);
        c = __builtin_amdgcn_mfma_f32_16x16x32_bf16(a1, bfrag[1], c, 0, 0, 0);
        c = __builtin_amdgcn_mfma_f32_16x16x32_bf16(a2, bfrag[2], c, 0, 0, 0);
        c = __builtin_amdgcn_mfma_f32_16x16x32_bf16(a3, bfrag[3], c, 0, 0, 0);

        #pragma unroll
        for (int r = 0; r < 4; ++r) {
            int orow = n0 + tt * 16 + quad * 4 + r;
            if (orow < N)
                out[(size_t)orow * DFEAT + nt * 16 + n15] = c[r] + bias;
        }
    }
}

extern "C" void kernel_launch(void* const* d_in, const int* in_sizes, int n_in,
                              void* d_out, int out_size, void* d_ws, size_t ws_size,
                              hipStream_t stream) {
    const float* x  = (const float*)d_in[0];
    const int*   ei = (const int*)d_in[1];     // [2,E] flat: src then dst
    const float* Wl = (const float*)d_in[2];
    const float* bl = (const float*)d_in[3];
    const float* Wr = (const float*)d_in[4];
    float* out = (float*)d_out;

    const int N = in_sizes[0] / DFEAT;         // 100000
    const int E = in_sizes[1] / 2;             // 1600000
    const int* src = ei;
    const int* dst = ei + E;

    const int nbuck = (N + 255) >> 8;          // 391 coarse buckets

    // ws: [bcnt 512][bfill 512][bbase 528][binned E][wl16 4096][wr16 4096][xh N*64]
    int* ws = (int*)d_ws;
    int* bcnt  = ws;
    int* bfill = bcnt + MAXBUCK;
    int* bbase = bfill + MAXBUCK;
    unsigned int* binned = (unsigned int*)(bbase + MAXBUCK + 16);
    unsigned short* wl16 = (unsigned short*)(binned + E);
    unsigned short* wr16 = wl16 + DFEAT * DFEAT;
    unsigned short* xh   = wr16 + DFEAT * DFEAT;

    hipMemsetAsync(bcnt, 0, 2 * MAXBUCK * sizeof(int), stream);

    int nx4 = N * DFEAT / 4;
    int convBlocks = (2048 + nx4 + 255) / 256;
    prep<<<convBlocks + 256, 256, 0, stream>>>(
        x, Wl, Wr, dst, xh, wl16, wr16, bcnt, nx4, convBlocks, E, nbuck);

    bscan<<<1, MAXBUCK, 0, stream>>>(bcnt, bbase, nbuck);
    binpass<<<256, 256, 0, stream>>>(src, dst, bbase, bfill, binned, E, nbuck);

    sage_fused<<<nbuck * 4, 256, 0, stream>>>(
        xh, binned, bbase, wl16, wr16, bl, out, N);
}